// Round 1
// baseline (106.630 us; speedup 1.0000x reference)
//
#include <hip/hip_runtime.h>
#include <math.h>

// QuantumLayer: proj = x@W.T + b; angles = sigmoid(proj*scale+bias)*pi;
// 8-qubit statevector sim (AngleEmbedding RY + 3x StronglyEntanglingLayers),
// output <Z_w> per wire. One 64-lane wave per batch element; 256 complex
// amplitudes held as 4 complex/lane in VGPRs. Wire w <-> bit (7-w) of the
// flat amplitude index i = lane*4 + k: wires 0..5 are lane bits (shfl_xor),
// wires 6..7 are the 2 local bits (register-only 2x2 mixes).

namespace {

constexpr float PI_F = 3.14159265358979323846f;

struct Cx { float re, im; };

__device__ __forceinline__ float shfx(float v, int m) {
  return __shfl_xor(v, m, 64);
}

// new_a = u00*a + u01*b ; new_b = u10*a + u11*b   (complex)
__device__ __forceinline__ void mix2(Cx &a, Cx &b,
    float u00r, float u00i, float u01r, float u01i,
    float u10r, float u10i, float u11r, float u11i) {
  float ar = a.re, ai = a.im, br = b.re, bi = b.im;
  a.re = u00r*ar - u00i*ai + u01r*br - u01i*bi;
  a.im = u00r*ai + u00i*ar + u01r*bi + u01i*br;
  b.re = u10r*ar - u10i*ai + u11r*br - u11i*bi;
  b.im = u10r*ai + u10i*ar + u11r*bi + u11i*br;
}

// Apply 2x2 unitary U on wire W (bit position 7-W of amplitude index).
template<int W>
__device__ __forceinline__ void apply1q(Cx s[4],
    float u00r, float u00i, float u01r, float u01i,
    float u10r, float u10i, float u11r, float u11i, int lane) {
  if constexpr (W == 7) {            // local bit 0: pairs (0,1),(2,3)
    mix2(s[0], s[1], u00r,u00i,u01r,u01i,u10r,u10i,u11r,u11i);
    mix2(s[2], s[3], u00r,u00i,u01r,u01i,u10r,u10i,u11r,u11i);
  } else if constexpr (W == 6) {     // local bit 1: pairs (0,2),(1,3)
    mix2(s[0], s[2], u00r,u00i,u01r,u01i,u10r,u10i,u11r,u11i);
    mix2(s[1], s[3], u00r,u00i,u01r,u01i,u10r,u10i,u11r,u11i);
  } else {                           // lane bit (5-W): exchange with partner lane
    constexpr int lm = 1 << (5 - W);
    const bool hi = (lane & lm) != 0;
    // mine is the bit=hi amplitude; theirs (from partner lane) is the other one.
    float cAr = hi ? u11r : u00r, cAi = hi ? u11i : u00i;  // coef of mine
    float cBr = hi ? u10r : u01r, cBi = hi ? u10i : u01i;  // coef of theirs
#pragma unroll
    for (int k = 0; k < 4; ++k) {
      float tr = shfx(s[k].re, lm), ti = shfx(s[k].im, lm);
      float mr = s[k].re, mi = s[k].im;
      s[k].re = cAr*mr - cAi*mi + cBr*tr - cBi*ti;
      s[k].im = cAr*mi + cAi*mr + cBr*ti + cBi*tr;
    }
  }
}

template<int W>
__device__ __forceinline__ void ryW(Cx s[4], float ang, int lane) {
  float h = 0.5f * ang;
  float c = __cosf(h), sn = __sinf(h);
  // RY = [[c,-s],[s,c]] (real) — zero imag parts fold away after inlining.
  apply1q<W>(s, c, 0.f, -sn, 0.f, sn, 0.f, c, 0.f, lane);
}

// PennyLane Rot = RZ(om) RY(th) RZ(phi); q_weights[L][W][0..2] = phi,th,om.
template<int L, int W>
__device__ __forceinline__ void rotW(Cx s[4], const float* __restrict__ qw, int lane) {
  float phi = qw[L*24 + W*3 + 0];
  float th  = qw[L*24 + W*3 + 1];
  float om  = qw[L*24 + W*3 + 2];
  float c  = __cosf(0.5f*th), sn = __sinf(0.5f*th);
  float a  = 0.5f*(phi + om), d = 0.5f*(phi - om);
  float ca = __cosf(a), sa = __sinf(a);
  float cd = __cosf(d), sd = __sinf(d);
  // u00 = c*e^{-ia}; u01 = -s*e^{+id}; u10 = s*e^{-id}; u11 = c*e^{+ia}
  apply1q<W>(s, c*ca, -c*sa, -sn*cd, -sn*sd, sn*cd, -sn*sd, c*ca, c*sa, lane);
}

__device__ __forceinline__ void swapc(Cx &a, Cx &b) { Cx t = a; a = b; b = t; }

__device__ __forceinline__ void cswap(Cx &a, Cx &b, bool c) {
  float ar = a.re, ai = a.im;
  a.re = c ? b.re : a.re;  a.im = c ? b.im : a.im;
  b.re = c ? ar : b.re;    b.im = c ? ai : b.im;
}

// CNOT(control wire CW, target wire TW): if bit(7-CW)==1, flip bit(7-TW).
template<int CW, int TW>
__device__ __forceinline__ void cnot(Cx s[4], int lane) {
  constexpr int pc = 7 - CW, pt = 7 - TW;
  if constexpr (pc >= 2 && pt >= 2) {
    // both bits live in the lane index
    constexpr int lmC = 1 << (pc - 2), lmT = 1 << (pt - 2);
    const bool ctl = (lane & lmC) != 0;
#pragma unroll
    for (int k = 0; k < 4; ++k) {
      float tr = shfx(s[k].re, lmT), ti = shfx(s[k].im, lmT);
      s[k].re = ctl ? tr : s[k].re;
      s[k].im = ctl ? ti : s[k].im;
    }
  } else if constexpr (pc >= 2 && pt < 2) {
    // control in lane bits, target local: conditional local swap
    constexpr int lmC = 1 << (pc - 2);
    const bool ctl = (lane & lmC) != 0;
    if constexpr (pt == 0) { cswap(s[0], s[1], ctl); cswap(s[2], s[3], ctl); }
    else                   { cswap(s[0], s[2], ctl); cswap(s[1], s[3], ctl); }
  } else if constexpr (pc < 2 && pt >= 2) {
    // control local, target in lane bits: the two local amps with control bit
    // set swap unconditionally with the partner lane.
    constexpr int lmT = 1 << (pt - 2);
    constexpr int k0 = (pc == 0) ? 1 : 2;  // local indices with bit pc set: {k0, 3}
    s[k0].re = shfx(s[k0].re, lmT); s[k0].im = shfx(s[k0].im, lmT);
    s[3].re  = shfx(s[3].re,  lmT); s[3].im  = shfx(s[3].im,  lmT);
  } else {
    // both local (wires 6,7)
    if constexpr (pc == 1) swapc(s[2], s[3]);  // ctl bit1 -> k=2,3; flip bit0
    else                   swapc(s[1], s[3]);  // ctl bit0 -> k=1,3; flip bit1
  }
}

template<int L>
__device__ __forceinline__ void rotLayer(Cx s[4], const float* __restrict__ qw, int lane) {
  rotW<L,0>(s, qw, lane); rotW<L,1>(s, qw, lane);
  rotW<L,2>(s, qw, lane); rotW<L,3>(s, qw, lane);
  rotW<L,4>(s, qw, lane); rotW<L,5>(s, qw, lane);
  rotW<L,6>(s, qw, lane); rotW<L,7>(s, qw, lane);
}

__global__ __launch_bounds__(256) void quantum_layer_kernel(
    const float* __restrict__ x, const float* __restrict__ Wm,
    const float* __restrict__ bvec, const float* __restrict__ scale,
    const float* __restrict__ bias, const float* __restrict__ qw,
    float* __restrict__ out) {
  const int tid  = threadIdx.x;
  const int lane = tid & 63;
  const int wv   = tid >> 6;
  const int b    = blockIdx.x * 4 + wv;   // batch element; grid covers 8192 exactly

  // ---- Phase 1: proj = x@W.T + b ; angles = sigmoid(proj*scale+bias)*pi ----
  const float4* x4 = (const float4*)(x + (size_t)b * 512);
  float4 xa = x4[lane];        // cols 4*lane .. 4*lane+3
  float4 xb = x4[64 + lane];   // cols 256+4*lane ..
  float ang[8];
#pragma unroll
  for (int q = 0; q < 8; ++q) {
    const float4* w4 = (const float4*)(Wm + q * 512);
    float4 wa = w4[lane];
    float4 wb = w4[64 + lane];
    ang[q] = xa.x*wa.x + xa.y*wa.y + xa.z*wa.z + xa.w*wa.w
           + xb.x*wb.x + xb.y*wb.y + xb.z*wb.z + xb.w*wb.w;
  }
#pragma unroll
  for (int off = 32; off >= 1; off >>= 1)
#pragma unroll
    for (int q = 0; q < 8; ++q)
      ang[q] += shfx(ang[q], off);
#pragma unroll
  for (int q = 0; q < 8; ++q) {
    float t = (ang[q] + bvec[q]) * scale[q] + bias[q];
    ang[q] = PI_F / (1.f + __expf(-t));   // sigmoid(t)*pi
  }

  // ---- Phase 2: statevector sim, 4 complex amps per lane ----
  Cx s[4];
#pragma unroll
  for (int k = 0; k < 4; ++k) { s[k].re = 0.f; s[k].im = 0.f; }
  s[0].re = (lane == 0) ? 1.f : 0.f;      // |0...0>

  // AngleEmbedding: RY(ang[w]) on wire w
  ryW<0>(s, ang[0], lane); ryW<1>(s, ang[1], lane);
  ryW<2>(s, ang[2], lane); ryW<3>(s, ang[3], lane);
  ryW<4>(s, ang[4], lane); ryW<5>(s, ang[5], lane);
  ryW<6>(s, ang[6], lane); ryW<7>(s, ang[7], lane);

  // Layer 0: Rot on all wires, CNOT ring r=1
  rotLayer<0>(s, qw, lane);
  cnot<0,1>(s, lane); cnot<1,2>(s, lane); cnot<2,3>(s, lane); cnot<3,4>(s, lane);
  cnot<4,5>(s, lane); cnot<5,6>(s, lane); cnot<6,7>(s, lane); cnot<7,0>(s, lane);

  // Layer 1: r=2
  rotLayer<1>(s, qw, lane);
  cnot<0,2>(s, lane); cnot<1,3>(s, lane); cnot<2,4>(s, lane); cnot<3,5>(s, lane);
  cnot<4,6>(s, lane); cnot<5,7>(s, lane); cnot<6,0>(s, lane); cnot<7,1>(s, lane);

  // Layer 2: r=3
  rotLayer<2>(s, qw, lane);
  cnot<0,3>(s, lane); cnot<1,4>(s, lane); cnot<2,5>(s, lane); cnot<3,6>(s, lane);
  cnot<4,7>(s, lane); cnot<5,0>(s, lane); cnot<6,1>(s, lane); cnot<7,2>(s, lane);

  // ---- Phase 3: <Z_w> = sum_i (-1)^{bit_{7-w}(i)} |amp_i|^2 ----
  float p0 = s[0].re*s[0].re + s[0].im*s[0].im;
  float p1 = s[1].re*s[1].re + s[1].im*s[1].im;
  float p2 = s[2].re*s[2].re + s[2].im*s[2].im;
  float p3 = s[3].re*s[3].re + s[3].im*s[3].im;
  float tot = p0 + p1 + p2 + p3;
  float z[8];
#pragma unroll
  for (int w = 0; w < 6; ++w)
    z[w] = ((lane >> (5 - w)) & 1) ? -tot : tot;
  z[6] = (p0 + p1) - (p2 + p3);   // local bit 1
  z[7] = (p0 - p1) + (p2 - p3);   // local bit 0
#pragma unroll
  for (int off = 32; off >= 1; off >>= 1)
#pragma unroll
    for (int w = 0; w < 8; ++w)
      z[w] += shfx(z[w], off);

  if (lane == 0) {
    float4* op = (float4*)(out + (size_t)b * 8);
    op[0] = make_float4(z[0], z[1], z[2], z[3]);
    op[1] = make_float4(z[4], z[5], z[6], z[7]);
  }
}

}  // namespace

extern "C" void kernel_launch(void* const* d_in, const int* in_sizes, int n_in,
                              void* d_out, int out_size, void* d_ws, size_t ws_size,
                              hipStream_t stream) {
  const float* x     = (const float*)d_in[0];  // (8192, 512)
  const float* Wm    = (const float*)d_in[1];  // (8, 512)
  const float* bvec  = (const float*)d_in[2];  // (8,)
  const float* scale = (const float*)d_in[3];  // (8,)
  const float* bias  = (const float*)d_in[4];  // (8,)
  const float* qw    = (const float*)d_in[5];  // (3, 8, 3)
  float* out = (float*)d_out;                  // (8192, 8)

  constexpr int BATCH = 8192;
  constexpr int WAVES_PER_BLOCK = 4;
  dim3 grid(BATCH / WAVES_PER_BLOCK), block(WAVES_PER_BLOCK * 64);
  hipLaunchKernelGGL(quantum_layer_kernel, grid, block, 0, stream,
                     x, Wm, bvec, scale, bias, qw, out);
}

// Round 2
// 100.227 us; speedup vs baseline: 1.0639x; 1.0639x over previous
//
#include <hip/hip_runtime.h>
#include <math.h>

// QuantumLayer, repacked: 16 complex amplitudes per lane, 4 batch elements
// per 64-lane wave (one batch element per 16-lane group).
// Amp index i (8 bits, wire w <-> bit 7-w):
//   bits 7..4 = lane&15  -> wires 0..3 are LANE wires (shfl_xor, mask 8/4/2/1)
//   bits 3..0 = k (0..15)-> wires 4..7 are LOCAL wires (register-only mixes)
// Per-wave work serves 4 batch elements -> ~3x less VALU+shfl per batch than
// the 4-amps/lane layout (round 1: 48us, VALUBusy 62%, HBM 2%).

namespace {

constexpr float PI_F = 3.14159265358979323846f;

struct Cx { float re, im; };

__device__ __forceinline__ float shfx(float v, int m) {
  return __shfl_xor(v, m, 64);
}

// new_a = u00*a + u01*b ; new_b = u10*a + u11*b   (complex)
__device__ __forceinline__ void mix2(Cx &a, Cx &b,
    float u00r, float u00i, float u01r, float u01i,
    float u10r, float u10i, float u11r, float u11i) {
  float ar = a.re, ai = a.im, br = b.re, bi = b.im;
  a.re = u00r*ar - u00i*ai + u01r*br - u01i*bi;
  a.im = u00r*ai + u00i*ar + u01r*bi + u01i*br;
  b.re = u10r*ar - u10i*ai + u11r*br - u11i*bi;
  b.im = u10r*ai + u10i*ar + u11r*bi + u11i*br;
}

// Apply 2x2 unitary on wire W. Zero-constant coefs fold after inlining.
template<int W>
__device__ __forceinline__ void apply1q(Cx s[16],
    float u00r, float u00i, float u01r, float u01i,
    float u10r, float u10i, float u11r, float u11i, int lane) {
  if constexpr (W >= 4) {                 // local bit lb = 7-W (3..0)
    constexpr int step = 1 << (7 - W);
#pragma unroll
    for (int k = 0; k < 16; ++k)
      if (!(k & step))
        mix2(s[k], s[k + step], u00r,u00i,u01r,u01i,u10r,u10i,u11r,u11i);
  } else {                                // lane bit 3-W
    constexpr int lm = 1 << (3 - W);
    const bool hi = (lane & lm) != 0;
    float cAr = hi ? u11r : u00r, cAi = hi ? u11i : u00i;  // coef of mine
    float cBr = hi ? u10r : u01r, cBi = hi ? u10i : u01i;  // coef of theirs
#pragma unroll
    for (int k = 0; k < 16; ++k) {
      float tr = shfx(s[k].re, lm), ti = shfx(s[k].im, lm);
      float mr = s[k].re, mi = s[k].im;
      s[k].re = cAr*mr - cAi*mi + cBr*tr - cBi*ti;
      s[k].im = cAr*mi + cAi*mr + cBr*ti + cBi*tr;
    }
  }
}

template<int W>
__device__ __forceinline__ void ryW(Cx s[16], float ang, int lane) {
  float h = 0.5f * ang;
  float c = __cosf(h), sn = __sinf(h);
  apply1q<W>(s, c, 0.f, -sn, 0.f, sn, 0.f, c, 0.f, lane);
}

// PennyLane Rot = RZ(om) RY(th) RZ(phi); qw[L][W][0..2] = phi,th,om.
template<int L, int W>
__device__ __forceinline__ void rotW(Cx s[16], const float* __restrict__ qw, int lane) {
  float phi = qw[L*24 + W*3 + 0];
  float th  = qw[L*24 + W*3 + 1];
  float om  = qw[L*24 + W*3 + 2];
  float c  = __cosf(0.5f*th), sn = __sinf(0.5f*th);
  float a  = 0.5f*(phi + om), d = 0.5f*(phi - om);
  float ca = __cosf(a), sa = __sinf(a);
  float cd = __cosf(d), sd = __sinf(d);
  // u00 = c*e^{-ia}; u01 = -s*e^{+id}; u10 = s*e^{-id}; u11 = c*e^{+ia}
  apply1q<W>(s, c*ca, -c*sa, -sn*cd, -sn*sd, sn*cd, -sn*sd, c*ca, c*sa, lane);
}

__device__ __forceinline__ void swapc(Cx &a, Cx &b) { Cx t = a; a = b; b = t; }

__device__ __forceinline__ void cswap(Cx &a, Cx &b, bool c) {
  float ar = a.re, ai = a.im;
  a.re = c ? b.re : a.re;  a.im = c ? b.im : a.im;
  b.re = c ? ar : b.re;    b.im = c ? ai : b.im;
}

// CNOT(CW, TW): if bit(7-CW)==1, flip bit(7-TW).
template<int CW, int TW>
__device__ __forceinline__ void cnot(Cx s[16], int lane) {
  constexpr int pc = 7 - CW, pt = 7 - TW;
  if constexpr (pc >= 4 && pt >= 4) {
    // both bits in lane nibble
    constexpr int lmC = 1 << (pc - 4), lmT = 1 << (pt - 4);
    const bool ctl = (lane & lmC) != 0;
#pragma unroll
    for (int k = 0; k < 16; ++k) {
      float tr = shfx(s[k].re, lmT), ti = shfx(s[k].im, lmT);
      s[k].re = ctl ? tr : s[k].re;
      s[k].im = ctl ? ti : s[k].im;
    }
  } else if constexpr (pc >= 4) {
    // lane control, local target: conditional local swap
    constexpr int lmC = 1 << (pc - 4), step = 1 << pt;
    const bool ctl = (lane & lmC) != 0;
#pragma unroll
    for (int k = 0; k < 16; ++k)
      if (!(k & step)) cswap(s[k], s[k + step], ctl);
  } else if constexpr (pt >= 4) {
    // local control, lane target: amps with ctl bit set swap with partner lane
    constexpr int lmT = 1 << (pt - 4), cb = 1 << pc;
#pragma unroll
    for (int k = 0; k < 16; ++k)
      if (k & cb) {
        s[k].re = shfx(s[k].re, lmT);
        s[k].im = shfx(s[k].im, lmT);
      }
  } else {
    // both local: pure register renames
    constexpr int cb = 1 << pc, tb = 1 << pt;
#pragma unroll
    for (int k = 0; k < 16; ++k)
      if ((k & cb) && !(k & tb)) swapc(s[k], s[k + tb]);
  }
}

template<int L>
__device__ __forceinline__ void rotLayer(Cx s[16], const float* __restrict__ qw, int lane) {
  rotW<L,0>(s, qw, lane); rotW<L,1>(s, qw, lane);
  rotW<L,2>(s, qw, lane); rotW<L,3>(s, qw, lane);
  rotW<L,4>(s, qw, lane); rotW<L,5>(s, qw, lane);
  rotW<L,6>(s, qw, lane); rotW<L,7>(s, qw, lane);
}

__global__ __launch_bounds__(256) void quantum_layer_kernel(
    const float* __restrict__ x, const float* __restrict__ Wm,
    const float* __restrict__ bvec, const float* __restrict__ scale,
    const float* __restrict__ bias, const float* __restrict__ qw,
    float* __restrict__ out) {
  const int tid  = threadIdx.x;
  const int lane = tid & 63;
  const int ll   = lane & 15;                    // lane within 16-lane group
  const int b    = blockIdx.x * 16 + (tid >> 4); // batch element

  // ---- Phase 1: proj = x@W.T + b ; angles = sigmoid(proj*scale+bias)*pi ----
  // 16 lanes per batch row; lane ll covers cols 4*(j*16+ll), j=0..7.
  const float4* x4 = (const float4*)(x + (size_t)b * 512);
  float4 xs[8];
#pragma unroll
  for (int j = 0; j < 8; ++j) xs[j] = x4[j * 16 + ll];
  const float4* W4 = (const float4*)Wm;
  float ang[8];
#pragma unroll
  for (int q = 0; q < 8; ++q) {
    float acc = 0.f;
#pragma unroll
    for (int j = 0; j < 8; ++j) {
      float4 w = W4[q * 128 + j * 16 + ll];
      acc += xs[j].x*w.x + xs[j].y*w.y + xs[j].z*w.z + xs[j].w*w.w;
    }
    ang[q] = acc;
  }
#pragma unroll
  for (int off = 8; off >= 1; off >>= 1)
#pragma unroll
    for (int q = 0; q < 8; ++q)
      ang[q] += shfx(ang[q], off);
#pragma unroll
  for (int q = 0; q < 8; ++q) {
    float t = (ang[q] + bvec[q]) * scale[q] + bias[q];
    ang[q] = PI_F / (1.f + __expf(-t));   // sigmoid(t)*pi
  }

  // ---- Phase 2: statevector sim, 16 complex amps per lane ----
  Cx s[16];
#pragma unroll
  for (int k = 0; k < 16; ++k) { s[k].re = 0.f; s[k].im = 0.f; }
  s[0].re = (ll == 0) ? 1.f : 0.f;        // |0...0>

  ryW<0>(s, ang[0], lane); ryW<1>(s, ang[1], lane);
  ryW<2>(s, ang[2], lane); ryW<3>(s, ang[3], lane);
  ryW<4>(s, ang[4], lane); ryW<5>(s, ang[5], lane);
  ryW<6>(s, ang[6], lane); ryW<7>(s, ang[7], lane);

  rotLayer<0>(s, qw, lane);   // r=1
  cnot<0,1>(s, lane); cnot<1,2>(s, lane); cnot<2,3>(s, lane); cnot<3,4>(s, lane);
  cnot<4,5>(s, lane); cnot<5,6>(s, lane); cnot<6,7>(s, lane); cnot<7,0>(s, lane);

  rotLayer<1>(s, qw, lane);   // r=2
  cnot<0,2>(s, lane); cnot<1,3>(s, lane); cnot<2,4>(s, lane); cnot<3,5>(s, lane);
  cnot<4,6>(s, lane); cnot<5,7>(s, lane); cnot<6,0>(s, lane); cnot<7,1>(s, lane);

  rotLayer<2>(s, qw, lane);   // r=3
  cnot<0,3>(s, lane); cnot<1,4>(s, lane); cnot<2,5>(s, lane); cnot<3,6>(s, lane);
  cnot<4,7>(s, lane); cnot<5,0>(s, lane); cnot<6,1>(s, lane); cnot<7,2>(s, lane);

  // ---- Phase 3: <Z_w> = sum_i (-1)^{bit_{7-w}(i)} |amp_i|^2 ----
  float p[16];
#pragma unroll
  for (int k = 0; k < 16; ++k) p[k] = s[k].re*s[k].re + s[k].im*s[k].im;

  // local wires 4..7 <-> k bits 3..0, via a signed reduction tree
  float q0[8], z7 = 0.f;
#pragma unroll
  for (int m = 0; m < 8; ++m) {
    q0[m] = p[2*m] + p[2*m+1];
    z7 += p[2*m] - p[2*m+1];
  }
  float q1[4], z6 = 0.f;
#pragma unroll
  for (int m = 0; m < 4; ++m) {
    q1[m] = q0[2*m] + q0[2*m+1];
    z6 += q0[2*m] - q0[2*m+1];
  }
  float q2a = q1[0] + q1[1], q2b = q1[2] + q1[3];
  float z5  = (q1[0] - q1[1]) + (q1[2] - q1[3]);
  float tot = q2a + q2b;
  float z4  = q2a - q2b;

  float z[8];
#pragma unroll
  for (int w = 0; w < 4; ++w)                  // lane wires 0..3 <-> lane bit 3-w
    z[w] = ((ll >> (3 - w)) & 1) ? -tot : tot;
  z[4] = z4; z[5] = z5; z[6] = z6; z[7] = z7;

#pragma unroll
  for (int off = 8; off >= 1; off >>= 1)
#pragma unroll
    for (int w = 0; w < 8; ++w)
      z[w] += shfx(z[w], off);

  if (ll == 0) {
    float4* op = (float4*)(out + (size_t)b * 8);
    op[0] = make_float4(z[0], z[1], z[2], z[3]);
    op[1] = make_float4(z[4], z[5], z[6], z[7]);
  }
}

}  // namespace

extern "C" void kernel_launch(void* const* d_in, const int* in_sizes, int n_in,
                              void* d_out, int out_size, void* d_ws, size_t ws_size,
                              hipStream_t stream) {
  const float* x     = (const float*)d_in[0];  // (8192, 512)
  const float* Wm    = (const float*)d_in[1];  // (8, 512)
  const float* bvec  = (const float*)d_in[2];  // (8,)
  const float* scale = (const float*)d_in[3];  // (8,)
  const float* bias  = (const float*)d_in[4];  // (8,)
  const float* qw    = (const float*)d_in[5];  // (3, 8, 3)
  float* out = (float*)d_out;                  // (8192, 8)

  constexpr int BATCH = 8192;
  // 256 threads = 4 waves = 16 batch elements per block
  dim3 grid(BATCH / 16), block(256);
  hipLaunchKernelGGL(quantum_layer_kernel, grid, block, 0, stream,
                     x, Wm, bvec, scale, bias, qw, out);
}